// Round 5
// baseline (87.405 us; speedup 1.0000x reference)
//
#include <hip/hip_runtime.h>
#include <hip/hip_bf16.h>
#include <math.h>

// logits [8,19,256,512] f32, targets [8,256,512] int32
// R=20 truncated EDT, loss = mean_b sum_c mean_hw probs*sdf
#define NCLS 19
#define BB   8
#define HH   256
#define WW   512
#define CAP2 400u     // R^2; any d >= 21 squares past this and is capped
#define SEG  8        // rows per kA segment

typedef unsigned short u16x2 __attribute__((ext_vector_type(2)));

static __device__ __forceinline__ unsigned umin32(unsigned a, unsigned b) { return a < b ? a : b; }
static __device__ __forceinline__ float fsqrt_fast(float x) { return __builtin_amdgcn_sqrtf(x); }

// ---------------------------------------------------------------------------
// Kernel A: vertical pass. vneg[b][c][h][w] = min |dh| with targ[h+dh][w]==c,
// UNcapped (<=50; kB's 400 cap on squares makes it equivalent). 8-row
// segments; static 29-iter scans (sentinel t=-1 out of range) fully unroll.
// ---------------------------------------------------------------------------
__global__ __launch_bounds__(256)
void kA_vert(const int* __restrict__ targ, unsigned char* __restrict__ vneg) {
    int gid = blockIdx.x * 256 + threadIdx.x;  // 4096 cols * 32 segs = 131072
    int col = gid & 4095;                      // lanes adjacent in w -> coalesced
    int seg = gid >> 12;                       // uniform within block
    int b = col >> 9;
    int w = col & 511;
    int h0 = seg * SEG;
    const int* tp = &targ[b * HH * WW + w];

    unsigned d[NCLS];
    unsigned pk[NCLS][2];   // 8 rows of u8 distances per class
#pragma unroll
    for (int c = 0; c < NCLS; ++c) { d[c] = 21u; pk[c][0] = 0u; pk[c][1] = 0u; }
#pragma unroll
    for (int k = 0; k < 21 + SEG; ++k) {
        int hh = h0 - 21 + k;
        int t = -1;
        if (hh >= 0) t = tp[hh * WW];          // uniform branch (top segs only)
#pragma unroll
        for (int c = 0; c < NCLS; ++c)
            d[c] = (t == c) ? 0u : d[c] + 1u;
        if (k >= 21) {
            int r = k - 21;
#pragma unroll
            for (int c = 0; c < NCLS; ++c)
                pk[c][r >> 2] |= d[c] << ((r & 3) * 8);
        }
    }

    unsigned u[NCLS];
#pragma unroll
    for (int c = 0; c < NCLS; ++c) u[c] = 21u;
#pragma unroll
    for (int k = 0; k < 21 + SEG; ++k) {
        int hh = h0 + 21 + SEG - 1 - k;
        int t = -1;
        if (hh < HH) t = tp[hh * WW];          // uniform branch (bottom segs)
#pragma unroll
        for (int c = 0; c < NCLS; ++c)
            u[c] = (t == c) ? 0u : u[c] + 1u;
        if (k >= 21) {
            int r = 21 + SEG - 1 - k;          // 7..0
#pragma unroll
            for (int c = 0; c < NCLS; ++c) {
                unsigned dv = (pk[c][r >> 2] >> ((r & 3) * 8)) & 0xffu;
                vneg[((size_t)(b * NCLS + c) * HH + hh) * WW + w] =
                    (unsigned char)umin32(dv, u[c]);
            }
        }
    }
}

// ---------------------------------------------------------------------------
// Kernel B: ONE WAVE (64 threads) per image row, 8 px/lane.
// LDS per class: 280 dwords (70 uint4): k = j+12 where j = pixel-word index
// (pixels 2j,2j+1 squared, packed u16). Halo j in [-12,0) and [256,268) = 441.
// Lane L: stages own words j=4L..4L+3 (one ds_write_b128 at uint4 idx L+3);
// reads window k=4L..4L+27 as 7 ds_read_b128 (uint4 idx L..L+6).
// Min-plus: acc_even/odd per output word, 21 taps, packed-u16 (1 op/tap),
// constants pinned in VGPRs. Fused softmax + loss; wave reduce; fixed-point
// atomic (deterministic).
// ---------------------------------------------------------------------------
#define WPC 70   // uint4 per class (280 dwords)

__global__ __launch_bounds__(64)
void kB_main(const float* __restrict__ logits, const int* __restrict__ targ,
             const unsigned char* __restrict__ vneg,
             unsigned long long* __restrict__ acc) {
    __shared__ uint4 lds4[NCLS * WPC];         // 21280 B
    unsigned* lds = (unsigned*)lds4;
    int bh = blockIdx.x;                       // 0..2047
    int b = bh >> 8;
    int h = bh & 255;
    int L = threadIdx.x;                       // 0..63

    // packed tap constants, pinned in VGPRs so they survive the class loop
    u16x2 Ce[21], Co[21];
#pragma unroll
    for (int m = 0; m < 21; ++m) {
        int o = m - 10;
        Ce[m] = (u16x2){(unsigned short)(4 * o * o),
                        (unsigned short)((2 * o + 1) * (2 * o + 1))};
        Co[m] = (u16x2){(unsigned short)((2 * o - 1) * (2 * o - 1)),
                        (unsigned short)(4 * o * o)};
        asm("" : "+v"(Ce[m]));
        asm("" : "+v"(Co[m]));
    }

    // halo fill: 24 words per class (k<12 and k>=268), value (441,441)
    const unsigned HALO2 = 441u | (441u << 16);
    for (int i = L; i < NCLS * 24; i += 64) {
        int c = i / 24, p = i % 24;
        lds[c * 280 + ((p < 12) ? p : 256 + p)] = HALO2;
    }

    // stage: per class, load 8 u8 vertical distances, square, pack, b128 write
    const uint2* vr = (const uint2*)vneg;
#pragma unroll
    for (int c = 0; c < NCLS; ++c) {
        uint2 v8 = vr[((size_t)(b * NCLS + c) * HH + h) * 64 + L];
        uint4 wq;
        {
            unsigned a = v8.x & 0x00FF00FFu;          // b0,b2
            unsigned bq = (v8.x >> 8) & 0x00FF00FFu;  // b1,b3
            u16x2 sa = __builtin_bit_cast(u16x2, a);  sa = sa * sa;
            u16x2 sb = __builtin_bit_cast(u16x2, bq); sb = sb * sb;
            unsigned ua = __builtin_bit_cast(unsigned, sa);
            unsigned ub = __builtin_bit_cast(unsigned, sb);
            wq.x = __builtin_amdgcn_perm(ub, ua, 0x05040100u);  // (b0^2,b1^2)
            wq.y = __builtin_amdgcn_perm(ub, ua, 0x07060302u);  // (b2^2,b3^2)
        }
        {
            unsigned a = v8.y & 0x00FF00FFu;
            unsigned bq = (v8.y >> 8) & 0x00FF00FFu;
            u16x2 sa = __builtin_bit_cast(u16x2, a);  sa = sa * sa;
            u16x2 sb = __builtin_bit_cast(u16x2, bq); sb = sb * sb;
            unsigned ua = __builtin_bit_cast(unsigned, sa);
            unsigned ub = __builtin_bit_cast(unsigned, sb);
            wq.z = __builtin_amdgcn_perm(ub, ua, 0x05040100u);
            wq.w = __builtin_amdgcn_perm(ub, ua, 0x07060302u);
        }
        lds4[c * WPC + L + 3] = wq;                   // k = 4L+12..4L+15
    }
    __syncthreads();

    // per-pixel state for 8 pixels (all indices compile-time via unroll)
    float den[8], num[8], et[8];
    unsigned m2[8];
#pragma unroll
    for (int p = 0; p < 8; ++p) { den[p] = 0.f; num[p] = 0.f; et[p] = 0.f; m2[p] = 0xFFFFu; }

    int t8[8];
    {
        const int4* tr = (const int4*)&targ[((size_t)b * HH + h) * WW + 8 * L];
        int4 ta = tr[0], tb = tr[1];
        t8[0]=ta.x; t8[1]=ta.y; t8[2]=ta.z; t8[3]=ta.w;
        t8[4]=tb.x; t8[5]=tb.y; t8[6]=tb.z; t8[7]=tb.w;
    }
    const float* lrow = &logits[((size_t)b * NCLS * HH + h) * WW + 8 * L];

#pragma unroll 1
    for (int c = 0; c < NCLS; ++c) {
        const float* lc = lrow + (size_t)c * (HH * WW);
        float4 f0 = *(const float4*)lc;
        float4 f1 = *(const float4*)(lc + 4);
        float fx[8] = {f0.x, f0.y, f0.z, f0.w, f1.x, f1.y, f1.z, f1.w};

        const uint4* basep = &lds4[c * WPC + L];
        uint4 q0 = basep[0], q1 = basep[1], q2 = basep[2], q3 = basep[3],
              q4 = basep[4], q5 = basep[5], q6 = basep[6];
        unsigned W[28] = {q0.x,q0.y,q0.z,q0.w, q1.x,q1.y,q1.z,q1.w,
                          q2.x,q2.y,q2.z,q2.w, q3.x,q3.y,q3.z,q3.w,
                          q4.x,q4.y,q4.z,q4.w, q5.x,q5.y,q5.z,q5.w,
                          q6.x,q6.y,q6.z,q6.w};

#pragma unroll
        for (int r = 0; r < 4; ++r) {
            u16x2 ae = {0xFFFF, 0xFFFF};
            u16x2 ao = {0xFFFF, 0xFFFF};
#pragma unroll
            for (int m = 0; m < 21; ++m) {
                u16x2 wv = __builtin_bit_cast(u16x2, W[r + m + 2]);
                ae = __builtin_elementwise_min(ae, (u16x2)(wv + Ce[m]));
                ao = __builtin_elementwise_min(ao, (u16x2)(wv + Co[m]));
            }
            unsigned nd0 = umin32((unsigned)ae.x, (unsigned)ae.y);  // px 8L+2r
            unsigned nd1 = umin32((unsigned)ao.x, (unsigned)ao.y);  // px 8L+2r+1

            float e0 = __expf(fx[2 * r]), e1 = __expf(fx[2 * r + 1]);
            den[2 * r] += e0; den[2 * r + 1] += e1;
            bool is0 = (c == t8[2 * r]), is1 = (c == t8[2 * r + 1]);
            float s0 = fsqrt_fast((float)umin32(nd0, CAP2));
            float s1 = fsqrt_fast((float)umin32(nd1, CAP2));
            num[2 * r]     += is0 ? 0.f : e0 * s0;
            num[2 * r + 1] += is1 ? 0.f : e1 * s1;
            et[2 * r]     = is0 ? e0 : et[2 * r];
            et[2 * r + 1] = is1 ? e1 : et[2 * r + 1];
            m2[2 * r]     = umin32(m2[2 * r],     is0 ? 0xFFFFu : nd0);
            m2[2 * r + 1] = umin32(m2[2 * r + 1], is1 ? 0xFFFFu : nd1);
        }
    }

    float v = 0.f;
#pragma unroll
    for (int p = 0; p < 8; ++p)
        v += (num[p] - et[p] * fsqrt_fast((float)umin32(m2[p], CAP2))) / den[p];

#pragma unroll
    for (int off = 32; off >= 1; off >>= 1) v += __shfl_down(v, off);
    if (L == 0) {
        // fixed-point 2^36 with /20 folded in; integer atomic => deterministic
        double q = (double)v * (68719476736.0 / 20.0);
        long long iv = (long long)q;
        atomicAdd(acc, (unsigned long long)iv);
    }
}

__global__ void kC_final(const unsigned long long* __restrict__ acc,
                         float* __restrict__ out) {
    long long iv = (long long)*acc;
    double v = (double)iv / 68719476736.0;
    out[0] = (float)(v / (double)((size_t)BB * HH * WW));
}

extern "C" void kernel_launch(void* const* d_in, const int* in_sizes, int n_in,
                              void* d_out, int out_size, void* d_ws, size_t ws_size,
                              hipStream_t stream) {
    const float* logits = (const float*)d_in[0];
    const int* targ = (const int*)d_in[1];
    unsigned char* wsb = (unsigned char*)d_ws;
    unsigned long long* acc = (unsigned long long*)wsb;       // [0,8)
    unsigned char* vneg = wsb + 64;                           // 19.9 MB u8

    (void)hipMemsetAsync(d_ws, 0, 64, stream);
    kA_vert<<<512, 256, 0, stream>>>(targ, vneg);             // 131072 threads
    kB_main<<<BB * HH, 64, 0, stream>>>(logits, targ, vneg, acc);
    kC_final<<<1, 1, 0, stream>>>(acc, (float*)d_out);
}

// Round 6
// 62.603 us; speedup vs baseline: 1.3962x; 1.3962x over previous
//
#include <hip/hip_runtime.h>
#include <hip/hip_bf16.h>
#include <math.h>

// logits [8,19,256,512] f32, targets [8,256,512] int32
// R=20 truncated EDT, loss = mean_b sum_c mean_hw probs*sdf
#define NCLS 19
#define BB   8
#define HH   256
#define WW   512
#define CAP2 400u     // R^2; any d >= 21 squares past this and is capped
#define SEG  8        // rows per kA segment

typedef unsigned short u16x2 __attribute__((ext_vector_type(2)));

static __device__ __forceinline__ unsigned umin32(unsigned a, unsigned b) { return a < b ? a : b; }
static __device__ __forceinline__ float fsqrt_fast(float x) { return __builtin_amdgcn_sqrtf(x); }

// packed u16 helpers. Constants go through "s" (SGPR) - scalar pipe, hoisted.
static __device__ __forceinline__ unsigned pk_add_s(unsigned v, unsigned c) {
    unsigned d; asm("v_pk_add_u16 %0, %1, %2" : "=v"(d) : "s"(c), "v"(v)); return d;
}
static __device__ __forceinline__ unsigned pk_minv(unsigned a, unsigned b) {
    unsigned d; asm("v_pk_min_u16 %0, %1, %2" : "=v"(d) : "v"(a), "v"(b)); return d;
}
static __device__ __forceinline__ unsigned pk_maxv(unsigned a, unsigned b) {
    unsigned d; asm("v_pk_max_u16 %0, %1, %2" : "=v"(d) : "v"(a), "v"(b)); return d;
}
// horizontal min of the two u16 halves, replicated into both halves
static __device__ __forceinline__ unsigned pk_hmin(unsigned a) {
    unsigned d;
    asm("v_pk_min_u16 %0, %1, %1 op_sel:[1,0] op_sel_hi:[0,1]" : "=v"(d) : "v"(a));
    return d;
}
// 4 u8 distances in x -> two packed-u16 squared words (w0=(b0^2,b1^2), w1=(b2^2,b3^2))
static __device__ __forceinline__ void sq8(unsigned x, unsigned& w0, unsigned& w1) {
    unsigned a = x & 0x00FF00FFu;
    unsigned b = (x >> 8) & 0x00FF00FFu;
    u16x2 sa = __builtin_bit_cast(u16x2, a); sa = sa * sa;
    u16x2 sb = __builtin_bit_cast(u16x2, b); sb = sb * sb;
    unsigned ua = __builtin_bit_cast(unsigned, sa);
    unsigned ub = __builtin_bit_cast(unsigned, sb);
    w0 = __builtin_amdgcn_perm(ub, ua, 0x05040100u);
    w1 = __builtin_amdgcn_perm(ub, ua, 0x07060302u);
}

// ---------------------------------------------------------------------------
// Kernel A: vertical pass (unchanged from round 5 - passed, ~15us).
// ---------------------------------------------------------------------------
__global__ __launch_bounds__(256)
void kA_vert(const int* __restrict__ targ, unsigned char* __restrict__ vneg) {
    int gid = blockIdx.x * 256 + threadIdx.x;
    int col = gid & 4095;
    int seg = gid >> 12;
    int b = col >> 9;
    int w = col & 511;
    int h0 = seg * SEG;
    const int* tp = &targ[b * HH * WW + w];

    unsigned d[NCLS];
    unsigned pk[NCLS][2];
#pragma unroll
    for (int c = 0; c < NCLS; ++c) { d[c] = 21u; pk[c][0] = 0u; pk[c][1] = 0u; }
#pragma unroll
    for (int k = 0; k < 21 + SEG; ++k) {
        int hh = h0 - 21 + k;
        int t = -1;
        if (hh >= 0) t = tp[hh * WW];
#pragma unroll
        for (int c = 0; c < NCLS; ++c)
            d[c] = (t == c) ? 0u : d[c] + 1u;
        if (k >= 21) {
            int r = k - 21;
#pragma unroll
            for (int c = 0; c < NCLS; ++c)
                pk[c][r >> 2] |= d[c] << ((r & 3) * 8);
        }
    }
    unsigned u[NCLS];
#pragma unroll
    for (int c = 0; c < NCLS; ++c) u[c] = 21u;
#pragma unroll
    for (int k = 0; k < 21 + SEG; ++k) {
        int hh = h0 + 21 + SEG - 1 - k;
        int t = -1;
        if (hh < HH) t = tp[hh * WW];
#pragma unroll
        for (int c = 0; c < NCLS; ++c)
            u[c] = (t == c) ? 0u : u[c] + 1u;
        if (k >= 21) {
            int r = 21 + SEG - 1 - k;
#pragma unroll
            for (int c = 0; c < NCLS; ++c) {
                unsigned dv = (pk[c][r >> 2] >> ((r & 3) * 8)) & 0xffu;
                vneg[((size_t)(b * NCLS + c) * HH + hh) * WW + w] =
                    (unsigned char)umin32(dv, u[c]);
            }
        }
    }
}

// ---------------------------------------------------------------------------
// Kernel B: one wave per row, 8 px/lane, NO LDS staging. Own v^2 words in
// registers; 24-word window built via 20 ds_bpermute + halo cndmask.
// S[i] = G[4L+i-10]; output even px const CE[m]=((2o)^2,(2o+1)^2), odd
// CO[m]=((2o-1)^2,(2o)^2), o=m-10, tap word S[r+m]. Center-out cascade:
// center |o|<=3, skip rest if all px partial <= 49 (remaining dx^2 >= 49);
// band2 |o| in 4..6, skip band3 if all <= 169. Exact for any input.
// ---------------------------------------------------------------------------
__global__ __launch_bounds__(256)
void kB_main(const float* __restrict__ logits, const int* __restrict__ targ,
             const unsigned char* __restrict__ vneg,
             unsigned long long* __restrict__ acc) {
    __shared__ float wsum[4];
    int tid = threadIdx.x;
    int L = tid & 63;
    int wid = tid >> 6;
    int bh = blockIdx.x * 4 + wid;     // row 0..2047
    int b = bh >> 8;
    int h = bh & 255;

    const unsigned HALO2 = 441u | (441u << 16);

#define SQx(x) ((unsigned)((x) * (x)))
#define PK2(a, bq) (SQx(a) | (SQx(bq) << 16))
    const unsigned CE[21] = {
        PK2(-20,-19), PK2(-18,-17), PK2(-16,-15), PK2(-14,-13), PK2(-12,-11),
        PK2(-10,-9),  PK2(-8,-7),   PK2(-6,-5),   PK2(-4,-3),   PK2(-2,-1),
        PK2(0,1),     PK2(2,3),     PK2(4,5),     PK2(6,7),     PK2(8,9),
        PK2(10,11),   PK2(12,13),   PK2(14,15),   PK2(16,17),   PK2(18,19),
        PK2(20,21) };
    const unsigned CO[21] = {
        PK2(-21,-20), PK2(-19,-18), PK2(-17,-16), PK2(-15,-14), PK2(-13,-12),
        PK2(-11,-10), PK2(-9,-8),   PK2(-7,-6),   PK2(-5,-4),   PK2(-3,-2),
        PK2(-1,0),    PK2(1,2),     PK2(3,4),     PK2(5,6),     PK2(7,8),
        PK2(9,10),    PK2(11,12),   PK2(13,14),   PK2(15,16),   PK2(17,18),
        PK2(19,20) };
#undef PK2
#undef SQx

    int im1 = ((L + 63) & 63) * 4, im2 = ((L + 62) & 63) * 4, im3 = ((L + 61) & 63) * 4;
    int ip1 = ((L + 1) & 63) * 4,  ip2 = ((L + 2) & 63) * 4,  ip3 = ((L + 3) & 63) * 4;

    const uint2* vr = (const uint2*)vneg + ((size_t)(b * NCLS) * HH + h) * 64 + L;
    const float* lrow = &logits[((size_t)(b * NCLS) * HH + h) * WW + 8 * L];

    int t8[8];
    {
        const int4* tr = (const int4*)&targ[((size_t)b * HH + h) * WW + 8 * L];
        int4 ta = tr[0], tb = tr[1];
        t8[0]=ta.x; t8[1]=ta.y; t8[2]=ta.z; t8[3]=ta.w;
        t8[4]=tb.x; t8[5]=tb.y; t8[6]=tb.z; t8[7]=tb.w;
    }

    float den[8], num[8], et[8];
    unsigned m2[8];
#pragma unroll
    for (int p = 0; p < 8; ++p) { den[p]=0.f; num[p]=0.f; et[p]=0.f; m2[p]=0xFFFFu; }

    // class-ahead prefetch
    uint2 v8n = vr[0];
    float4 f0n = *(const float4*)lrow;
    float4 f1n = *(const float4*)(lrow + 4);

#pragma unroll 1
    for (int c = 0; c < NCLS; ++c) {
        uint2 v8 = v8n;
        float4 f0 = f0n, f1 = f1n;
        int cn = (c < NCLS - 1) ? c + 1 : c;
        v8n = vr[(size_t)cn * (HH * 64)];
        f0n = *(const float4*)(lrow + (size_t)cn * (HH * WW));
        f1n = *(const float4*)(lrow + (size_t)cn * (HH * WW) + 4);

        unsigned o0, o1, o2, o3;
        sq8(v8.x, o0, o1);
        sq8(v8.y, o2, o3);

        unsigned S[24];
        S[10] = o0; S[11] = o1; S[12] = o2; S[13] = o3;
        unsigned t;
        t = __builtin_amdgcn_ds_bpermute(im1, (int)o3); S[9]  = (L >= 1) ? t : HALO2;
        t = __builtin_amdgcn_ds_bpermute(im1, (int)o2); S[8]  = (L >= 1) ? t : HALO2;
        t = __builtin_amdgcn_ds_bpermute(im1, (int)o1); S[7]  = (L >= 1) ? t : HALO2;
        t = __builtin_amdgcn_ds_bpermute(im1, (int)o0); S[6]  = (L >= 1) ? t : HALO2;
        t = __builtin_amdgcn_ds_bpermute(im2, (int)o3); S[5]  = (L >= 2) ? t : HALO2;
        t = __builtin_amdgcn_ds_bpermute(im2, (int)o2); S[4]  = (L >= 2) ? t : HALO2;
        t = __builtin_amdgcn_ds_bpermute(im2, (int)o1); S[3]  = (L >= 2) ? t : HALO2;
        t = __builtin_amdgcn_ds_bpermute(im2, (int)o0); S[2]  = (L >= 2) ? t : HALO2;
        t = __builtin_amdgcn_ds_bpermute(im3, (int)o3); S[1]  = (L >= 3) ? t : HALO2;
        t = __builtin_amdgcn_ds_bpermute(im3, (int)o2); S[0]  = (L >= 3) ? t : HALO2;
        t = __builtin_amdgcn_ds_bpermute(ip1, (int)o0); S[14] = (L <= 62) ? t : HALO2;
        t = __builtin_amdgcn_ds_bpermute(ip1, (int)o1); S[15] = (L <= 62) ? t : HALO2;
        t = __builtin_amdgcn_ds_bpermute(ip1, (int)o2); S[16] = (L <= 62) ? t : HALO2;
        t = __builtin_amdgcn_ds_bpermute(ip1, (int)o3); S[17] = (L <= 62) ? t : HALO2;
        t = __builtin_amdgcn_ds_bpermute(ip2, (int)o0); S[18] = (L <= 61) ? t : HALO2;
        t = __builtin_amdgcn_ds_bpermute(ip2, (int)o1); S[19] = (L <= 61) ? t : HALO2;
        t = __builtin_amdgcn_ds_bpermute(ip2, (int)o2); S[20] = (L <= 61) ? t : HALO2;
        t = __builtin_amdgcn_ds_bpermute(ip2, (int)o3); S[21] = (L <= 61) ? t : HALO2;
        t = __builtin_amdgcn_ds_bpermute(ip3, (int)o0); S[22] = (L <= 60) ? t : HALO2;
        t = __builtin_amdgcn_ds_bpermute(ip3, (int)o1); S[23] = (L <= 60) ? t : HALO2;

        unsigned ae[4], ao[4];
#pragma unroll
        for (int r = 0; r < 4; ++r) { ae[r] = 0xFFFFFFFFu; ao[r] = 0xFFFFFFFFu; }

        // center band: m = 7..13  (|dx| <= 5 evens / <= 7 partial)
#pragma unroll
        for (int r = 0; r < 4; ++r)
#pragma unroll
            for (int m = 7; m <= 13; ++m) {
                ae[r] = pk_minv(ae[r], pk_add_s(S[r + m], CE[m]));
                ao[r] = pk_minv(ao[r], pk_add_s(S[r + m], CO[m]));
            }

        unsigned mx = pk_maxv(pk_maxv(pk_maxv(pk_hmin(ae[0]), pk_hmin(ao[0])),
                                      pk_maxv(pk_hmin(ae[1]), pk_hmin(ao[1]))),
                              pk_maxv(pk_maxv(pk_hmin(ae[2]), pk_hmin(ao[2])),
                                      pk_maxv(pk_hmin(ae[3]), pk_hmin(ao[3]))));
        if (!__all(mx <= (49u | (49u << 16)))) {
            // band2: m in {4,5,6,14,15,16} (remaining tap dx^2 >= 49)
#pragma unroll
            for (int r = 0; r < 4; ++r) {
#pragma unroll
                for (int m = 4; m <= 6; ++m) {
                    ae[r] = pk_minv(ae[r], pk_add_s(S[r + m], CE[m]));
                    ao[r] = pk_minv(ao[r], pk_add_s(S[r + m], CO[m]));
                }
#pragma unroll
                for (int m = 14; m <= 16; ++m) {
                    ae[r] = pk_minv(ae[r], pk_add_s(S[r + m], CE[m]));
                    ao[r] = pk_minv(ao[r], pk_add_s(S[r + m], CO[m]));
                }
            }
            mx = pk_maxv(pk_maxv(pk_maxv(pk_hmin(ae[0]), pk_hmin(ao[0])),
                                 pk_maxv(pk_hmin(ae[1]), pk_hmin(ao[1]))),
                         pk_maxv(pk_maxv(pk_hmin(ae[2]), pk_hmin(ao[2])),
                                 pk_maxv(pk_hmin(ae[3]), pk_hmin(ao[3]))));
            if (!__all(mx <= (169u | (169u << 16)))) {
                // band3: m in {0..3, 17..20} (remaining tap dx^2 >= 169)
#pragma unroll
                for (int r = 0; r < 4; ++r) {
#pragma unroll
                    for (int m = 0; m <= 3; ++m) {
                        ae[r] = pk_minv(ae[r], pk_add_s(S[r + m], CE[m]));
                        ao[r] = pk_minv(ao[r], pk_add_s(S[r + m], CO[m]));
                    }
#pragma unroll
                    for (int m = 17; m <= 20; ++m) {
                        ae[r] = pk_minv(ae[r], pk_add_s(S[r + m], CE[m]));
                        ao[r] = pk_minv(ao[r], pk_add_s(S[r + m], CO[m]));
                    }
                }
            }
        }

        float fx[8] = {f0.x, f0.y, f0.z, f0.w, f1.x, f1.y, f1.z, f1.w};
#pragma unroll
        for (int r = 0; r < 4; ++r) {
            unsigned nd0 = pk_hmin(ae[r]) & 0xFFFFu;   // px 8L+2r
            unsigned nd1 = pk_hmin(ao[r]) & 0xFFFFu;   // px 8L+2r+1
            float e0 = __expf(fx[2 * r]), e1 = __expf(fx[2 * r + 1]);
            den[2 * r] += e0; den[2 * r + 1] += e1;
            bool is0 = (c == t8[2 * r]), is1 = (c == t8[2 * r + 1]);
            float s0 = fsqrt_fast((float)umin32(nd0, CAP2));
            float s1 = fsqrt_fast((float)umin32(nd1, CAP2));
            num[2 * r]     += is0 ? 0.f : e0 * s0;
            num[2 * r + 1] += is1 ? 0.f : e1 * s1;
            et[2 * r]     = is0 ? e0 : et[2 * r];
            et[2 * r + 1] = is1 ? e1 : et[2 * r + 1];
            m2[2 * r]     = umin32(m2[2 * r],     is0 ? 0xFFFFu : nd0);
            m2[2 * r + 1] = umin32(m2[2 * r + 1], is1 ? 0xFFFFu : nd1);
        }
    }

    float v = 0.f;
#pragma unroll
    for (int p = 0; p < 8; ++p)
        v += (num[p] - et[p] * fsqrt_fast((float)umin32(m2[p], CAP2))) / den[p];

#pragma unroll
    for (int off = 32; off >= 1; off >>= 1) v += __shfl_down(v, off);
    if (L == 0) wsum[wid] = v;
    __syncthreads();
    if (tid == 0) {
        float s = wsum[0] + wsum[1] + wsum[2] + wsum[3];
        // fixed-point 2^36 with /20 folded in; integer atomic => deterministic
        double q = (double)s * (68719476736.0 / 20.0);
        long long iv = (long long)q;
        atomicAdd(acc, (unsigned long long)iv);
    }
}

__global__ void kC_final(const unsigned long long* __restrict__ acc,
                         float* __restrict__ out) {
    long long iv = (long long)*acc;
    double v = (double)iv / 68719476736.0;
    out[0] = (float)(v / (double)((size_t)BB * HH * WW));
}

extern "C" void kernel_launch(void* const* d_in, const int* in_sizes, int n_in,
                              void* d_out, int out_size, void* d_ws, size_t ws_size,
                              hipStream_t stream) {
    const float* logits = (const float*)d_in[0];
    const int* targ = (const int*)d_in[1];
    unsigned char* wsb = (unsigned char*)d_ws;
    unsigned long long* acc = (unsigned long long*)wsb;       // [0,8)
    unsigned char* vneg = wsb + 64;                           // 19.9 MB u8

    (void)hipMemsetAsync(d_ws, 0, 64, stream);
    kA_vert<<<512, 256, 0, stream>>>(targ, vneg);             // 131072 threads
    kB_main<<<512, 256, 0, stream>>>(logits, targ, vneg, acc); // 4 rows/block
    kC_final<<<1, 1, 0, stream>>>(acc, (float*)d_out);
}